// Round 2
// baseline (324.964 us; speedup 1.0000x reference)
//
#include <hip/hip_runtime.h>

// burst:   (nd=32, c=3, 128, 128) fp32
// kernels: (nd=32, r=4, 5, 5, 128, 128) fp32
// out:     (nd=32, c=3, 256, 256) fp32 (pixel-shuffle s=2)
#define HH 128
#define WW 128
#define CC 3
#define RR 4
#define KK 5
#define ND 32
#define HW (HH * WW)

#define TROWS 12              // 8 compute rows + 4 halo
#define TS    132             // tile row stride in floats (128 + 4 halo), mult of 4
#define TSIZE (CC * TROWS * TS)  // 4752 floats = 19 KB

__global__ __launch_bounds__(256, 4) void adaptive_conv_ps(
    const float* __restrict__ burst,
    const float* __restrict__ kern,
    float* __restrict__ out)
{
    __shared__ float tile[TSIZE];

    const int tid = threadIdx.x;
    const int nd  = blockIdx.x >> 4;         // 32 nd slices
    const int h0  = (blockIdx.x & 15) << 3;  // 8 output rows per block

    // ---- Stage burst tile (3 x 12 x 132) into LDS, zero-padded halo ----
    const float* bbase = burst + (size_t)nd * CC * HW;
    for (int idx = tid; idx < TSIZE; idx += 256) {
        int c   = idx / (TROWS * TS);
        int rem = idx - c * (TROWS * TS);
        int row = rem / TS;
        int col = rem - row * TS;
        int y = h0 - 2 + row;
        int x = col - 2;
        float v = 0.0f;
        if ((unsigned)y < (unsigned)HH && (unsigned)x < (unsigned)WW)
            v = bbase[c * HW + y * WW + x];
        tile[idx] = v;
    }
    __syncthreads();

    // ---- Each thread: 4 consecutive w pixels on one row ----
    const int lrow = tid >> 5;          // 0..7  (local row)
    const int w0   = (tid & 31) << 2;   // 0,4,...,124
    const int h    = h0 + lrow;

    const float* kbase = kern + (size_t)nd * RR * KK * KK * HW + h * WW + w0;

    float acc[CC][RR][4];
#pragma unroll
    for (int c = 0; c < CC; ++c)
#pragma unroll
        for (int r = 0; r < RR; ++r)
#pragma unroll
            for (int p = 0; p < 4; ++p)
                acc[c][r][p] = 0.0f;

    for (int i = 0; i < KK; ++i) {
        // 8-float burst row window per channel, aligned b128 LDS reads.
        // tile col for (tap j, pixel p) = w0 + j + p  ∈ [w0, w0+7]
        float rowv[CC][8];
#pragma unroll
        for (int c = 0; c < CC; ++c) {
            const float4* rp =
                (const float4*)&tile[c * TROWS * TS + (lrow + i) * TS + w0];
            *(float4*)&rowv[c][0] = rp[0];
            *(float4*)&rowv[c][4] = rp[1];
        }
#pragma unroll
        for (int j = 0; j < KK; ++j) {
            float kv[RR][4];
#pragma unroll
            for (int r = 0; r < RR; ++r)
                *(float4*)kv[r] =
                    *(const float4*)(kbase + (size_t)((r * KK + i) * KK + j) * HW);
#pragma unroll
            for (int c = 0; c < CC; ++c)
#pragma unroll
                for (int r = 0; r < RR; ++r)
#pragma unroll
                    for (int p = 0; p < 4; ++p)
                        acc[c][r][p] += kv[r][p] * rowv[c][j + p];
        }
    }

    // ---- Pixel-shuffle store: out[nd,c,2h+si, 2(w0+p)+sj] = acc[c][si*2+sj][p]
#pragma unroll
    for (int c = 0; c < CC; ++c) {
#pragma unroll
        for (int si = 0; si < 2; ++si) {
            float4 v0, v1;
            v0.x = acc[c][si * 2 + 0][0]; v0.y = acc[c][si * 2 + 1][0];
            v0.z = acc[c][si * 2 + 0][1]; v0.w = acc[c][si * 2 + 1][1];
            v1.x = acc[c][si * 2 + 0][2]; v1.y = acc[c][si * 2 + 1][2];
            v1.z = acc[c][si * 2 + 0][3]; v1.w = acc[c][si * 2 + 1][3];
            float* o = out + (((size_t)(nd * CC + c) * (2 * HH) + (2 * h + si)) * (2 * WW))
                           + 2 * w0;
            ((float4*)o)[0] = v0;
            ((float4*)o)[1] = v1;
        }
    }
}

extern "C" void kernel_launch(void* const* d_in, const int* in_sizes, int n_in,
                              void* d_out, int out_size, void* d_ws, size_t ws_size,
                              hipStream_t stream) {
    const float* burst = (const float*)d_in[0];
    const float* kern  = (const float*)d_in[1];
    float* out = (float*)d_out;

    // 512 blocks: 32 nd slices x 16 row-groups (8 rows each); 256 thr, 4 px/thr
    adaptive_conv_ps<<<ND * 16, 256, 0, stream>>>(burst, kern, out);
}

// Round 3
// 315.809 us; speedup vs baseline: 1.0290x; 1.0290x over previous
//
#include <hip/hip_runtime.h>

// burst:   (nd=32, c=3, 128, 128) fp32
// kernels: (nd=32, r=4, 5, 5, 128, 128) fp32
// out:     (nd=32, c=3, 256, 256) fp32 (pixel-shuffle s=2)
#define HH 128
#define WW 128
#define CC 3
#define RR 4
#define KK 5
#define ND 32
#define HW (HH * WW)

#define ROWS_PER_BLK 4
#define TROWS (ROWS_PER_BLK + 4)   // 8: 4 compute rows + 4 halo
#define TS    132                  // 128 + 4 halo, even (float2-aligned)
#define TSIZE (CC * TROWS * TS)    // 3168 floats = 12.7 KB

__global__ __launch_bounds__(256, 4) void adaptive_conv_ps(
    const float* __restrict__ burst,
    const float* __restrict__ kern,
    float* __restrict__ out)
{
    __shared__ float tile[TSIZE];

    const int tid = threadIdx.x;
    const int nd  = blockIdx.x >> 5;                 // 0..31
    const int h0  = (blockIdx.x & 31) * ROWS_PER_BLK;

    // ---- Stage burst tile (3 x 8 x 132) into LDS, zero-padded halo ----
    const float* bbase = burst + (size_t)nd * CC * HW;
    for (int idx = tid; idx < TSIZE; idx += 256) {
        int c   = idx / (TROWS * TS);
        int rem = idx - c * (TROWS * TS);
        int row = rem / TS;
        int col = rem - row * TS;
        int y = h0 - 2 + row;
        int x = col - 2;
        float v = 0.0f;
        if ((unsigned)y < (unsigned)HH && (unsigned)x < (unsigned)WW)
            v = bbase[c * HW + y * WW + x];
        tile[idx] = v;
    }
    __syncthreads();

    // ---- One wave per row; each thread does 2 consecutive w pixels ----
    const int lrow = tid >> 6;          // 0..3
    const int lane = tid & 63;
    const int w0   = lane << 1;         // 0,2,...,126
    const int h    = h0 + lrow;

    const float* kbase = kern + (size_t)nd * RR * KK * KK * HW + h * WW + w0;

    float acc[CC][RR][2];
#pragma unroll
    for (int c = 0; c < CC; ++c)
#pragma unroll
        for (int r = 0; r < RR; ++r) {
            acc[c][r][0] = 0.0f;
            acc[c][r][1] = 0.0f;
        }

#pragma unroll
    for (int i = 0; i < KK; ++i) {
        // 6-float burst window per channel: cols w0 .. w0+5 (tile is shifted +2,
        // so tile col w0+t corresponds to image col w0+t-2). float2 reads,
        // 8 B/lane stride -> 2-way bank alias (free).
        float rowv[CC][6];
#pragma unroll
        for (int c = 0; c < CC; ++c) {
            const float2* rp =
                (const float2*)&tile[c * TROWS * TS + (lrow + i) * TS + w0];
            *(float2*)&rowv[c][0] = rp[0];
            *(float2*)&rowv[c][2] = rp[1];
            *(float2*)&rowv[c][4] = rp[2];
        }
#pragma unroll
        for (int j = 0; j < KK; ++j) {
            float2 kv[RR];
#pragma unroll
            for (int r = 0; r < RR; ++r)
                kv[r] = *(const float2*)(kbase + (size_t)((r * KK + i) * KK + j) * HW);
#pragma unroll
            for (int c = 0; c < CC; ++c)
#pragma unroll
                for (int r = 0; r < RR; ++r) {
                    acc[c][r][0] += kv[r].x * rowv[c][j + 0];
                    acc[c][r][1] += kv[r].y * rowv[c][j + 1];
                }
        }
    }

    // ---- Pixel-shuffle store: out[nd,c,2h+si, 2(w0+p)+sj] = acc[c][si*2+sj][p]
#pragma unroll
    for (int c = 0; c < CC; ++c) {
#pragma unroll
        for (int si = 0; si < 2; ++si) {
            float4 v;
            v.x = acc[c][si * 2 + 0][0];
            v.y = acc[c][si * 2 + 1][0];
            v.z = acc[c][si * 2 + 0][1];
            v.w = acc[c][si * 2 + 1][1];
            float* o = out + (((size_t)(nd * CC + c) * (2 * HH) + (2 * h + si)) * (2 * WW))
                           + 2 * w0;
            *(float4*)o = v;
        }
    }
}

extern "C" void kernel_launch(void* const* d_in, const int* in_sizes, int n_in,
                              void* d_out, int out_size, void* d_ws, size_t ws_size,
                              hipStream_t stream) {
    const float* burst = (const float*)d_in[0];
    const float* kern  = (const float*)d_in[1];
    float* out = (float*)d_out;

    // 1024 blocks: 32 nd x 32 row-groups (4 rows each); 256 thr, 2 px/thr
    adaptive_conv_ps<<<ND * 32, 256, 0, stream>>>(burst, kern, out);
}